// Round 11
// baseline (716.942 us; speedup 1.0000x reference)
//
#include <hip/hip_runtime.h>

// GCMC GraphConv layer, MI355X (gfx950) — CSR (counting-sort) version.
// h[dst] = sum_r ( (sum_{e: dst,r} x[src_e]) / c[dst,r] ) @ W[r]
//
// 1. memset cnt/cursor (1.2 MB)
// 2. hist: per-edge atomicAdd into cnt_u[u], cnt_v[v]
// 3. scan1/scan2/scan3: exclusive prefix sum cnt -> base (per direction)
// 4. fill_csr: slot = base[d] + atomicAdd(cur[d]); csr[slot] = (src<<3)|rate
// 5. aggregate_csr: wave per dst node; SEQUENTIAL adjacency read (packed 4B),
//    coalesced 256B x-row gathers, per-rating named-register accumulate,
//    write accum[d,r,:] = sum/max(c,1) with plain stores
// 6. transform_v3: h[d] = sum_r accum[d,r,:] @ W[r]; W column in VGPRs,
//    wave-uniform float4 A loads, pure v_fmac. No LDS in hot kernels.
// Users processed in 2 chunks of 50K over one 64 MB accum buffer (ws ~74 MB).

constexpr int FEAT  = 64;
constexpr int RC    = 5;
constexpr int STRIP = 16;
constexpr int CHUNK = 50000;

// ---------- phase 2: degree histogram ----------
__global__ __launch_bounds__(256) void hist(
    const int* __restrict__ u_s, const int* __restrict__ v_s,
    int* __restrict__ cnt_u, int* __restrict__ cnt_v, int n_edges)
{
  const int e = blockIdx.x * blockDim.x + threadIdx.x;
  if (e >= n_edges) return;
  atomicAdd(&cnt_u[u_s[e]], 1);
  atomicAdd(&cnt_v[v_s[e]], 1);
}

// ---------- phase 3: exclusive scan (3 kernels, 256/block Hillis-Steele) ----------
__global__ __launch_bounds__(256) void scan1(
    const int* __restrict__ in, int* __restrict__ out_local,
    int* __restrict__ bsum, int n)
{
  __shared__ int s[256];
  const int tid = threadIdx.x;
  const int i = blockIdx.x * 256 + tid;
  const int v = (i < n) ? in[i] : 0;
  s[tid] = v; __syncthreads();
#pragma unroll
  for (int off = 1; off < 256; off <<= 1) {
    const int t = (tid >= off) ? s[tid - off] : 0;
    __syncthreads();
    s[tid] += t;
    __syncthreads();
  }
  if (i < n) out_local[i] = s[tid] - v;          // block-local exclusive
  if (tid == 255) bsum[blockIdx.x] = s[255];     // block total
}

__global__ __launch_bounds__(256) void scan2(int* __restrict__ bsum, int nb)
{
  __shared__ int s[256];
  const int tid = threadIdx.x;
  int carry = 0;
  for (int start = 0; start < nb; start += 256) {
    const int i = start + tid;
    const int v = (i < nb) ? bsum[i] : 0;
    s[tid] = v; __syncthreads();
#pragma unroll
    for (int off = 1; off < 256; off <<= 1) {
      const int t = (tid >= off) ? s[tid - off] : 0;
      __syncthreads();
      s[tid] += t;
      __syncthreads();
    }
    const int total = s[255];                    // stable: loop ends in sync
    if (i < nb) bsum[i] = carry + s[tid] - v;    // exclusive across chunks
    carry += total;
    __syncthreads();                             // before s reuse
  }
}

__global__ __launch_bounds__(256) void scan3(
    int* __restrict__ base, const int* __restrict__ bsum, int n)
{
  const int i = blockIdx.x * 256 + threadIdx.x;
  if (i < n) base[i] += bsum[blockIdx.x];
}

// ---------- phase 4: CSR fill (both directions) ----------
__global__ __launch_bounds__(256) void fill_csr(
    const int* __restrict__ u_s, const int* __restrict__ v_s,
    const int* __restrict__ rate,
    const int* __restrict__ base_u, const int* __restrict__ base_v,
    int* __restrict__ cur_u, int* __restrict__ cur_v,
    int* __restrict__ csr_u, int* __restrict__ csr_v, int n_edges)
{
  const int e = blockIdx.x * blockDim.x + threadIdx.x;
  if (e >= n_edges) return;
  const int u = u_s[e], v = v_s[e], r = rate[e];
  const int pu = base_u[u] + atomicAdd(&cur_u[u], 1);
  csr_u[pu] = (v << 3) | r;                      // user-dir source = item
  const int pv = base_v[v] + atomicAdd(&cur_v[v], 1);
  csr_v[pv] = (u << 3) | r;                      // item-dir source = user
}

// ---------- phase 5: gather-aggregate over sequential CSR ----------
__global__ __launch_bounds__(256) void aggregate_csr(
    const float* __restrict__ src_x,    // [n_src, FEAT]
    const int* __restrict__ csr,        // packed (src<<3)|rate, CSR order
    const int* __restrict__ base,       // [n_dst] CSR offsets
    const int* __restrict__ cnt,        // [n_dst] degrees
    float* __restrict__ accum,          // [node_count, RC, FEAT] chunk-local
    int node_base, int node_count)
{
  const int lane = threadIdx.x & 63;
  const int w    = (blockIdx.x * blockDim.x + threadIdx.x) >> 6;
  if (w >= node_count) return;
  const int d   = node_base + w;
  const int off = base[d];
  const int deg = cnt[d];

  float a0 = 0.f, a1 = 0.f, a2 = 0.f, a3 = 0.f, a4 = 0.f;
  int   c0 = 0,   c1 = 0,   c2 = 0,   c3 = 0,   c4 = 0;

  for (int i = 0; i < deg; ++i) {
    const unsigned p = (unsigned)csr[off + i];   // uniform sequential 4B
    const int s = (int)(p >> 3);
    const int r = (int)(p & 7u);
    const float xv = src_x[(size_t)s * FEAT + lane];  // coalesced 256B row
    a0 += (r == 0) ? xv : 0.f;  c0 += (r == 0);
    a1 += (r == 1) ? xv : 0.f;  c1 += (r == 1);
    a2 += (r == 2) ? xv : 0.f;  c2 += (r == 2);
    a3 += (r == 3) ? xv : 0.f;  c3 += (r == 3);
    a4 += (r == 4) ? xv : 0.f;  c4 += (r == 4);
  }

  float* row = accum + (size_t)w * RC * FEAT + lane;
  row[0 * FEAT] = a0 / (float)(c0 > 0 ? c0 : 1);
  row[1 * FEAT] = a1 / (float)(c1 > 0 ? c1 : 1);
  row[2 * FEAT] = a2 / (float)(c2 > 0 ? c2 : 1);
  row[3 * FEAT] = a3 / (float)(c3 > 0 ? c3 : 1);
  row[4 * FEAT] = a4 / (float)(c4 > 0 ? c4 : 1);
}

// ---------- phase 6: dense transform (unchanged from round 7) ----------
__global__ __launch_bounds__(256) void transform_v3(
    const float* __restrict__ accum,   // [node_count, RC, FEAT]
    const float* __restrict__ W,       // [RC, FEAT, FEAT] (r, in, out)
    float* __restrict__ out,           // [node_count, FEAT]
    int node_count)
{
  const int lane = threadIdx.x & 63;
  const int wid  = (blockIdx.x * blockDim.x + threadIdx.x) >> 6;
  const int nw   = (gridDim.x * blockDim.x) >> 6;

  for (int base = wid * STRIP; base < node_count; base += nw * STRIP) {
    const int base_u = __builtin_amdgcn_readfirstlane(base);
    float o_acc[STRIP];
#pragma unroll
    for (int n = 0; n < STRIP; ++n) o_acc[n] = 0.f;

    for (int r = 0; r < RC; ++r) {
      float wcol[FEAT];
#pragma unroll
      for (int k = 0; k < FEAT; ++k)
        wcol[k] = W[((size_t)r * FEAT + k) * FEAT + lane];

#pragma unroll
      for (int n = 0; n < STRIP; ++n) {
        const int node = base_u + n;
        if (node >= node_count) break;
        const float4* ap4 = reinterpret_cast<const float4*>(
            accum + ((size_t)node * RC + r) * FEAT);
        float t = 0.f;
#pragma unroll
        for (int k4 = 0; k4 < FEAT / 4; ++k4) {
          const float4 a = ap4[k4];
          t = fmaf(a.x, wcol[k4 * 4 + 0], t);
          t = fmaf(a.y, wcol[k4 * 4 + 1], t);
          t = fmaf(a.z, wcol[k4 * 4 + 2], t);
          t = fmaf(a.w, wcol[k4 * 4 + 3], t);
        }
        o_acc[n] += t;
      }
    }
#pragma unroll
    for (int n = 0; n < STRIP; ++n) {
      if (base + n < node_count)
        out[(size_t)(base + n) * FEAT + lane] = o_acc[n];
    }
  }
}

extern "C" void kernel_launch(void* const* d_in, const int* in_sizes, int n_in,
                              void* d_out, int out_size, void* d_ws, size_t ws_size,
                              hipStream_t stream) {
  const float* user_x = (const float*)d_in[0];
  const float* item_x = (const float*)d_in[1];
  const float* weight = (const float*)d_in[2];
  const int*   u_s    = (const int*)d_in[3];
  const int*   v_s    = (const int*)d_in[4];
  const int*   rate   = (const int*)d_in[5];

  const int n_users = in_sizes[0] / FEAT;   // 100000
  const int n_items = in_sizes[1] / FEAT;   // 50000
  const int n_edges = in_sizes[3];          // 1000000

  float* out = (float*)d_out;
  float* h_u = out;
  float* h_v = out + (size_t)n_users * FEAT;

  // Workspace (~74 MB):
  // [ accum 64MB | cnt_u cnt_v cur_u cur_v | base_u base_v | bsum_u bsum_v | csr_u csr_v ]
  float* accum  = (float*)d_ws;
  int*   cnt_u  = (int*)(accum + (size_t)CHUNK * RC * FEAT);
  int*   cnt_v  = cnt_u + n_users;
  int*   cur_u  = cnt_v + n_items;
  int*   cur_v  = cur_u + n_users;
  int*   base_u = cur_v + n_items;
  int*   base_v = base_u + n_users;
  int*   bsum_u = base_v + n_items;
  int*   bsum_v = bsum_u + 512;
  int*   csr_u  = bsum_v + 512;
  int*   csr_v  = csr_u + n_edges;

  const int nb_u = (n_users + 255) / 256;   // 391
  const int nb_v = (n_items + 255) / 256;   // 196
  const int gE   = (n_edges + 255) / 256;

  // zero cnt + cur in one memset (contiguous)
  hipMemsetAsync(cnt_u, 0,
                 (size_t)2 * (n_users + n_items) * sizeof(int), stream);

  hist<<<gE, 256, 0, stream>>>(u_s, v_s, cnt_u, cnt_v, n_edges);

  scan1<<<nb_u, 256, 0, stream>>>(cnt_u, base_u, bsum_u, n_users);
  scan1<<<nb_v, 256, 0, stream>>>(cnt_v, base_v, bsum_v, n_items);
  scan2<<<1, 256, 0, stream>>>(bsum_u, nb_u);
  scan2<<<1, 256, 0, stream>>>(bsum_v, nb_v);
  scan3<<<nb_u, 256, 0, stream>>>(base_u, bsum_u, n_users);
  scan3<<<nb_v, 256, 0, stream>>>(base_v, bsum_v, n_items);

  fill_csr<<<gE, 256, 0, stream>>>(u_s, v_s, rate, base_u, base_v,
                                   cur_u, cur_v, csr_u, csr_v, n_edges);

  // ---- users (items -> users), 2 chunks over one accum buffer ----
  for (int cb = 0; cb < n_users; cb += CHUNK) {
    const int cnt = (n_users - cb < CHUNK) ? (n_users - cb) : CHUNK;
    aggregate_csr<<<(cnt + 3) / 4, 256, 0, stream>>>(
        item_x, csr_u, base_u, cnt_u, accum, cb, cnt);
    transform_v3<<<(cnt + 63) / 64, 256, 0, stream>>>(
        accum, weight, h_u + (size_t)cb * FEAT, cnt);
  }

  // ---- items (users -> items) ----
  for (int cb = 0; cb < n_items; cb += CHUNK) {
    const int cnt = (n_items - cb < CHUNK) ? (n_items - cb) : CHUNK;
    aggregate_csr<<<(cnt + 3) / 4, 256, 0, stream>>>(
        user_x, csr_v, base_v, cnt_v, accum, cb, cnt);
    transform_v3<<<(cnt + 63) / 64, 256, 0, stream>>>(
        accum, weight, h_v + (size_t)cb * FEAT, cnt);
  }

  (void)ws_size; (void)n_in; (void)out_size;
}